// Round 16
// baseline (303.324 us; speedup 1.0000x reference)
//
#include <hip/hip_runtime.h>
#include <hip/hip_bf16.h>
#include <hip/hip_fp8.h>

#define NROWS 16384
#define DDIM  256
#define LOG2E 1.44269504088896f
#define LN2   0.69314718055995f

typedef __attribute__((ext_vector_type(8))) int ix8;      // 32B = 8 VGPR
typedef __attribute__((ext_vector_type(4))) short bh4;    // fallback use
typedef __attribute__((ext_vector_type(4))) float fx4;
typedef __attribute__((ext_vector_type(16))) float fx16;  // 32x32 accumulator

__device__ __forceinline__ short f2bf(float x) {
  __hip_bfloat16 h = __float2bfloat16(x);
  return *reinterpret_cast<short*>(&h);
}

__device__ __forceinline__ float fexp2(float x) {
#if __has_builtin(__builtin_amdgcn_exp2f)
  return __builtin_amdgcn_exp2f(x);   // v_exp_f32: D = 2^S0
#else
  return __expf(x * 0.6931471805599453f);
#endif
}

__device__ __forceinline__ fx16 fzero16() {
  fx16 z;
#pragma unroll
  for (int q = 0; q < 16; ++q) z[q] = 0.f;
  return z;
}

// exact softplus, used only on the 16384 diagonal elements
__device__ __forceinline__ float softplus_f(float y) {
  float a = fabsf(y);
  float t = __expf(-a);
  float l;
  if (t < 0.125f) {
    l = t * (1.0f - t * (0.5f - 0.333333333f * t));
  } else {
    l = log1pf(t);
  }
  return fmaxf(y, 0.0f) + l;
}

// fp32 -> fp8 e4m3 (OCP), 8 elements/thread, optional pre-scale.
// Pre-scaling A by k1 = scale*log2e makes the GEMM emit k1*c directly:
// the epilogue's per-element mul disappears (2.68e8 muls ~ 15us VALU).
// fp8 relative precision is scale-invariant, so accuracy is unchanged.
__global__ void cast_fp8_kernel(const float* __restrict__ in,
                                unsigned char* __restrict__ out,
                                const float* __restrict__ scale_p,
                                int do_scale) {
  const float s = do_scale ? (*scale_p * LOG2E) : 1.0f;
  int i = (blockIdx.x * blockDim.x + threadIdx.x) * 8;
  float4 v0 = *(const float4*)(in + i);
  float4 v1 = *(const float4*)(in + i + 4);
  unsigned r0 = (unsigned)__hip_fp8_e4m3(v0.x * s).__x |
                ((unsigned)__hip_fp8_e4m3(v0.y * s).__x << 8) |
                ((unsigned)__hip_fp8_e4m3(v0.z * s).__x << 16) |
                ((unsigned)__hip_fp8_e4m3(v0.w * s).__x << 24);
  unsigned r1 = (unsigned)__hip_fp8_e4m3(v1.x * s).__x |
                ((unsigned)__hip_fp8_e4m3(v1.y * s).__x << 8) |
                ((unsigned)__hip_fp8_e4m3(v1.z * s).__x << 16) |
                ((unsigned)__hip_fp8_e4m3(v1.w * s).__x << 24);
  uint2 r; r.x = r0; r.y = r1;
  *(uint2*)(out + i) = r;
}

// ============ persistent strip: fp8 MX 32x32x64, 4 blocks/CU ==============
// 1024 blocks (4/CU, launch_bounds(256,4) -> VGPR cap 128; R14 kernel is
// ~112), 256 threads = 4 waves (2 wr x 2 wc), wave tile 64x64 of
// mfma_scale_f32_32x32x64_f8f6f4 (scale=1 -> plain fp8 e4m3, 2x bf16 rate).
// Block = 128 img rows x 2048 txt cols; cg = bid&7 is XCD-PINNED (all blocks
// on XCD k share B panel k: 512KB << 4MB L2); rp = bid>>3.
// A (pre-scaled by k1) resident in 64 regs/wave. LDS 32KB: B ring 4 x 8KB,
// k-half-major layout (conflict-minimal). 64 chunks of 128 cols x K=64.
// Chunk t: [vmcnt(4) | barrier | fence | 2 ix8 reads | STAGE S(t+3) | 4 MFMA]
// R15->R16: dropped null frag-dbuf; 4 blocks/CU fills the ~1/3 dual-pipe
// idle (MfmaUtil 30 + VALUBusy 36) with real wave parallelism; epilogue is
// now exp2+add only (mul folded into cast).

#define MFMA_SC(A_, B_, C_)                                                    \
  __builtin_amdgcn_mfma_scale_f32_32x32x64_f8f6f4((A_), (B_), (C_), 0, 0, 0,  \
                                                  sc1, 0, sc1)

// stage chunk (bt2,kc2) into buffer bufp (2 x global_load_lds / thread).
// dest slot (it*4096 + wave*1024 + lane*16) holds content:
//   h = wave>>1, c = (wave&1)*32 + (lane>>1), sub16 = lane&1
#define STAGE(bt2, kc2, bufp)                                                  \
  do {                                                                         \
    _Pragma("unroll")                                                          \
    for (int it_ = 0; it_ < 2; ++it_) {                                        \
      __builtin_amdgcn_global_load_lds(                                        \
          (const __attribute__((address_space(1))) void*)(                     \
              Bm +                                                             \
              (size_t)(colgbase + (bt2) * 128 + it_ * 64 + (wave & 1) * 32 +   \
                       (lane >> 1)) * 256 +                                    \
              (kc2) * 64 + (wave >> 1) * 32 + (lane & 1) * 16),                \
          (__attribute__((address_space(3))) void*)((bufp) + it_ * 4096 +      \
                                                    wave * 1024 + lane * 16),  \
          16, 0, 0);                                                           \
    }                                                                          \
  } while (0)

#define CHUNKF(kc, rbuf, VM, DO_ST, SBT, SKC, sq)                              \
  do {                                                                         \
    asm volatile("s_waitcnt vmcnt(%0)" ::"i"(VM) : "memory");                  \
    __builtin_amdgcn_s_barrier();                                              \
    asm volatile("" ::: "memory"); /* no LDS reads above the barrier */        \
    ix8 b0_ = *(const ix8*)((rbuf) + bb);                                      \
    ix8 b1_ = *(const ix8*)((rbuf) + 1024 + bb);                               \
    if (DO_ST) STAGE(SBT, SKC, sq);                                            \
    acc00 = MFMA_SC(areg[0][kc], b0_, acc00);                                  \
    acc01 = MFMA_SC(areg[0][kc], b1_, acc01);                                  \
    acc10 = MFMA_SC(areg[1][kc], b0_, acc10);                                  \
    acc11 = MFMA_SC(areg[1][kc], b1_, acc11);                                  \
  } while (0)

// per-tile epilogue for one 32x32 acc; acc already holds k1*c (A pre-scaled).
// C layout (m74/m101): col = lane&31, row = (reg&3) + 8*(reg>>2) + 4*(lane>>5)
#define EPI32(A_, m_, n_)                                                      \
  do {                                                                         \
    fx16 v_ = A_;                                                              \
    A_ = fzero16();                                                            \
    _Pragma("unroll")                                                          \
    for (int g_ = 0; g_ < 16; g_ += 4) {                                       \
      e0 += fexp2(v_[g_ + 0]);                                                 \
      e1 += fexp2(v_[g_ + 1]);                                                 \
      e2 += fexp2(v_[g_ + 2]);                                                 \
      e3 += fexp2(v_[g_ + 3]);                                                 \
    }                                                                          \
    if (dtile) { /* block-uniform: at most 1 of 16 tiles */                    \
      const int gcol_ = colbase + wc * 64 + (n_) * 32 + (lane & 31);           \
      const int grow0_ = rowbase + wr * 64 + (m_) * 32 + 4 * hi;               \
      _Pragma("unroll")                                                        \
      for (int r_ = 0; r_ < 16; ++r_) {                                        \
        int grow_ = grow0_ + (r_ & 3) + 8 * (r_ >> 2);                         \
        if (grow_ == gcol_) {                                                  \
          d += softplus_f(-fmaf(v_[r_], LN2, bias));  /* scale*c = v*ln2 */    \
          e0 -= fexp2(v_[r_]);                                                 \
        }                                                                      \
      }                                                                        \
    }                                                                          \
  } while (0)

#define EPILOGUE(btv)                                                          \
  do {                                                                         \
    const int colbase = colgbase + (btv) * 128;                                \
    const bool dtile = (colbase == rowbase);                                   \
    EPI32(acc00, 0, 0); EPI32(acc01, 0, 1);                                    \
    EPI32(acc10, 1, 0); EPI32(acc11, 1, 1);                                    \
  } while (0)

__global__ __launch_bounds__(256, 4) void siglip_strip(
    const unsigned char* __restrict__ Am, const unsigned char* __restrict__ Bm,
    const float* __restrict__ scale_p, const float* __restrict__ bias_p,
    float* __restrict__ out) {
  __shared__ char lds[32768];    // B ring: 4 x 8KB
  char* q0 = lds;
  char* q1 = lds + 8192;
  char* q2 = lds + 16384;
  char* q3 = lds + 24576;

  const int tid  = threadIdx.x;
  const int lane = tid & 63;
  const int wave = tid >> 6;     // 0..3
  const int wr   = wave >> 1;    // 0..1
  const int wc   = wave & 1;     // 0..1
  // XCD-pinned col group: all blocks on XCD k read B panel k (L2-resident).
  const int bid  = blockIdx.x;
  const int cg   = bid & 7;      // 0..7
  const int rp   = bid >> 3;     // 0..127
  const int rowbase  = rp * 128;
  const int colgbase = cg * 2048;

  const int hi  = lane >> 5;          // 0/1
  // read base (k-half-major layout): wc*4096 + hi*2048 + (lane&31)*32;
  // n=0 at +0, n=1 at +1024. Lane stride 32B -> conflict-minimal.
  const int bb  = wc * 4096 + hi * 2048 + (lane & 31) * 32;
  const int sc1 = 0x7F7F7F7F;         // e8m0 scale 1.0 in every byte

  const float bias = *bias_p;     // uniform -> SGPR (lgkm domain)
  const float eb = fexp2((*scale_p) * 0.0f + bias * LOG2E);  // e^bias

  // ---- prologue: A slice into registers (8 x 32B loads, static indices) ---
  ix8 areg[2][4];
  {
    const unsigned char* Aw = Am + (size_t)(rowbase + wr * 64) * 256;
#pragma unroll
    for (int m = 0; m < 2; ++m)
#pragma unroll
      for (int kc = 0; kc < 4; ++kc)
        areg[m][kc] = *(const ix8*)(Aw + (size_t)(m * 32 + (lane & 31)) * 256 +
                                    kc * 64 + hi * 32);
  }
  // drain all prologue vmem so counted vmcnt below sees only staging loads
  asm volatile("s_waitcnt vmcnt(0)" ::: "memory");

  STAGE(0, 0, q0);  // chunk 0
  STAGE(0, 1, q1);  // chunk 1
  STAGE(0, 2, q2);  // chunk 2

  fx16 acc00 = fzero16(), acc01 = fzero16();
  fx16 acc10 = fzero16(), acc11 = fzero16();
  float e0 = 0.f, e1 = 0.f, e2 = 0.f, e3 = 0.f, d = 0.f;

  for (int bt = 0; bt < 15; ++bt) {
    CHUNKF(0, q0, 4, 1, bt,     3, q3);  // t=4bt+0, stage t+3 -> q3
    CHUNKF(1, q1, 4, 1, bt + 1, 0, q0);  // t=4bt+1, stage -> q0
    CHUNKF(2, q2, 4, 1, bt + 1, 1, q1);  // t=4bt+2, stage -> q1
    CHUNKF(3, q3, 4, 1, bt + 1, 2, q2);  // t=4bt+3, stage -> q2
    EPILOGUE(bt);  // register-only; overlaps in-flight DMA
  }
  // ---- peeled bt = 15 (chunks 60..63) ----
  CHUNKF(0, q0, 4, 1, 15, 3, q3);  // stage chunk 63
  CHUNKF(1, q1, 4, 0, 0, 0, q0);
  CHUNKF(2, q2, 2, 0, 0, 0, q0);
  CHUNKF(3, q3, 0, 0, 0, 0, q0);
  EPILOGUE(15);

  float local = fmaf((e0 + e1) + (e2 + e3), eb, d);
#pragma unroll
  for (int off = 32; off > 0; off >>= 1) local += __shfl_xor(local, off, 64);

  __syncthreads();  // LDS reuse for block reduction
  float* red = (float*)lds;
  if (lane == 0) red[wave] = local;
  __syncthreads();
  if (tid == 0)
    atomicAdd(out, ((red[0] + red[1]) + (red[2] + red[3])) * (1.0f / 16384.0f));
}

// ===================== fallback: f32 inputs, reg-staged (no ws needed) =====
__device__ __forceinline__ unsigned swz256(unsigned o) {
  return o ^ (((o >> 8) & 7u) << 4);
}

__device__ __forceinline__ void map_tile(int bid, int& tr, int& tc) {
  int xcd = bid & 7;
  int idx = bid >> 3;
  int g   = idx >> 7;
  int w   = idx & 127;
  tr = xcd * 16 + (w >> 3);
  tc = g * 8 + (w & 7);
}

typedef __attribute__((ext_vector_type(8))) short bh8;

__global__ __launch_bounds__(256, 2) void siglip_fallback(
    const float* __restrict__ A, const float* __restrict__ B,
    const float* __restrict__ scale_p, const float* __restrict__ bias_p,
    float* __restrict__ out) {
  __shared__ char lds[65536];
  char* ldsA = lds;
  char* ldsB = lds + 32768;
  const int tid  = threadIdx.x;
  const int lane = tid & 63;
  const int wave = tid >> 6;
  const int wr   = wave >> 1;
  const int wc   = wave & 1;
  int tr, tc;
  map_tile(blockIdx.x, tr, tc);
  const int brow = tr * 128, bcol = tc * 128;

  fx4 acc[4][4];
#pragma unroll
  for (int m = 0; m < 4; ++m)
#pragma unroll
    for (int n = 0; n < 4; ++n) acc[m][n] = (fx4){0.f, 0.f, 0.f, 0.f};

#pragma unroll
  for (int p = 0; p < 2; ++p) {
    __syncthreads();
    const float* Af = A + (size_t)brow * DDIM + p * 128;
    const float* Bf = B + (size_t)bcol * DDIM + p * 128;
#pragma unroll
    for (int it = 0; it < 16; ++it) {
      int c = it * 256 + tid;
      int row = c >> 5, j = c & 31;
      unsigned o = row * 256 + j * 8;
      {
        float4 v = *(const float4*)(Af + (size_t)row * DDIM + j * 4);
        bh4 h;
        h[0] = f2bf(v.x); h[1] = f2bf(v.y); h[2] = f2bf(v.z); h[3] = f2bf(v.w);
        *(bh4*)(ldsA + swz256(o)) = h;
      }
      {
        float4 v = *(const float4*)(Bf + (size_t)row * DDIM + j * 4);
        bh4 h;
        h[0] = f2bf(v.x); h[1] = f2bf(v.y); h[2] = f2bf(v.z); h[3] = f2bf(v.w);
        *(bh4*)(ldsB + swz256(o)) = h;
      }
    }
    __syncthreads();
#pragma unroll
    for (int kk = 0; kk < 4; ++kk) {
      const int colb = kk * 64 + (lane >> 4) * 16;
      bh8 a[4], b[4];
#pragma unroll
      for (int m = 0; m < 4; ++m) {
        int r = wr * 64 + m * 16 + (lane & 15);
        a[m] = *(const bh8*)(ldsA + swz256((unsigned)(r * 256 + colb)));
      }
#pragma unroll
      for (int n = 0; n < 4; ++n) {
        int r = wc * 64 + n * 16 + (lane & 15);
        b[n] = *(const bh8*)(ldsB + swz256((unsigned)(r * 256 + colb)));
      }
#pragma unroll
      for (int m = 0; m < 4; ++m)
#pragma unroll
        for (int n = 0; n < 4; ++n)
          acc[m][n] = __builtin_amdgcn_mfma_f32_16x16x32_bf16(a[m], b[n],
                                                              acc[m][n], 0, 0, 0);
    }
  }

  const float scale = *scale_p;
  const float bias  = *bias_p;
  const float k1 = scale * LOG2E;
  const float k0 = bias * LOG2E;
  float s0 = 0.f, s1 = 0.f, s2 = 0.f, s3 = 0.f;
  const int  row0 = brow + wr * 64 + (lane >> 4) * 4;
  const int  col0 = bcol + wc * 64 + (lane & 15);
  const bool isdiag = (tr == tc);
#pragma unroll
  for (int m = 0; m < 4; ++m) {
#pragma unroll
    for (int n = 0; n < 4; ++n) {
      fx4 v = acc[m][n];
      s0 += fexp2(fmaf(k1, v[0], k0));
      s1 += fexp2(fmaf(k1, v[1], k0));
      s2 += fexp2(fmaf(k1, v[2], k0));
      s3 += fexp2(fmaf(k1, v[3], k0));
      if (isdiag) {
        const int gj = col0 + n * 16;
#pragma unroll
        for (int j = 0; j < 4; ++j) {
          const int gi = row0 + m * 16 + j;
          if (gi == gj) {
            float logit = fmaf(scale, v[j], bias);
            s0 += softplus_f(-logit) - fexp2(fmaf(k1, v[j], k0));
          }
        }
      }
    }
  }
  float local = (s0 + s1) + (s2 + s3);
#pragma unroll
  for (int off = 32; off > 0; off >>= 1) local += __shfl_xor(local, off, 64);

  __syncthreads();
  float* red = (float*)lds;
  if (lane == 0) red[wave] = local;
  __syncthreads();
  if (tid == 0)
    atomicAdd(out, (red[0] + red[1] + red[2] + red[3]) * (1.0f / 16384.0f));
}

extern "C" void kernel_launch(void* const* d_in, const int* in_sizes, int n_in,
                              void* d_out, int out_size, void* d_ws,
                              size_t ws_size, hipStream_t stream) {
  const float* img     = (const float*)d_in[0];
  const float* txt     = (const float*)d_in[1];
  const float* scale_p = (const float*)d_in[2];
  const float* bias_p  = (const float*)d_in[3];
  float* out = (float*)d_out;

  hipMemsetAsync(d_out, 0, (size_t)out_size * sizeof(float), stream);

  const size_t elems = (size_t)NROWS * DDIM;               // 4.19M
  const size_t need  = 2 * elems * sizeof(unsigned char);  // 8.4 MB

  if (ws_size >= need) {
    unsigned char* A8 = (unsigned char*)d_ws;
    unsigned char* B8 = A8 + elems;
    const int cast_blocks = (int)(elems / (256 * 8));  // 2048
    cast_fp8_kernel<<<cast_blocks, 256, 0, stream>>>(img, A8, scale_p, 1);
    cast_fp8_kernel<<<cast_blocks, 256, 0, stream>>>(txt, B8, scale_p, 0);
    siglip_strip<<<1024, 256, 0, stream>>>(A8, B8, scale_p, bias_p, out);
    return;
  }
  const int nblocks = (NROWS / 128) * (NROWS / 128);  // 16384
  siglip_fallback<<<nblocks, 256, 0, stream>>>(img, txt, scale_p, bias_p, out);
}